// Round 15
// baseline (574.202 us; speedup 1.0000x reference)
//
#include <hip/hip_runtime.h>

// ---------------------------------------------------------------------------
// Sparse UNet forward — round 22: MT=4 half-tap A-dbuf (r18) + phase-blocked
// LDS B (r21) — the two independently-verified wins, stacked.
//   r21 post-mortem: barriers irrelevant (27->9 = -2%); occupancy irrelevant
//   (r19); three structures plateau 87-93us => shared scattered-line fetch
//   cost. MT=4 halves wave count (halves queue pressure) and doubles MFMA
//   per gather batch; LDS-B keeps B off the global path.
//   TPP: conv2=2 (32KB), conv1=4 (16KB), down=4 (32KB, 1 barrier), conv3=4
//   (32KB). Expected VGPR ~104 (r18 measured this exact reg structure).
// ---------------------------------------------------------------------------

#define EPS 1e-4f

typedef __attribute__((ext_vector_type(8))) short short8;   // 8 x bf16
typedef __attribute__((ext_vector_type(4))) float f32x4;

__device__ __forceinline__ unsigned short f2bf(float f) {
    union { float f; unsigned int u; } v; v.f = f;
    unsigned int r = v.u + 0x7fffu + ((v.u >> 16) & 1u);   // RNE
    return (unsigned short)(r >> 16);
}

__global__ void zero_kernel(float* p, long n) {
    long i = (long)blockIdx.x * 256 + threadIdx.x;
    if (i < n) p[i] = 0.f;
}

// Per-channel sum / sumsq -> stats[0:C], stats[C:2C] (atomic accumulate).
template <int C>
__global__ __launch_bounds__(256) void bn_stats(const float* __restrict__ x,
                                                int rows, int stride,
                                                float* __restrict__ stats) {
    const int tid = threadIdx.x;
    const int c = tid & (C - 1);
    const int g = tid / C;
    const int GR = 256 / C;
    float s = 0.f, s2 = 0.f;
    for (int r = blockIdx.x * GR + g; r < rows; r += gridDim.x * GR) {
        float v = x[(size_t)r * stride + c];
        s += v; s2 += v * v;
    }
    __shared__ float sh[2][256];
    sh[0][tid] = s; sh[1][tid] = s2;
    __syncthreads();
    for (int off = 128; off >= C; off >>= 1) {
        if (tid < off) { sh[0][tid] += sh[0][tid + off]; sh[1][tid] += sh[1][tid + off]; }
        __syncthreads();
    }
    if (tid < C) {
        atomicAdd(&stats[c], sh[0][tid]);
        atomicAdd(&stats[C + c], sh[1][tid]);
    }
}

// BN finalize + ReLU -> bf16. Output packed (rows+1) x C, sentinel row zeroed.
template <int C, int CSPLIT>
__global__ __launch_bounds__(256) void bn_norm_relu_bf16(
    const float* __restrict__ x, int rows, int stride,
    const float* __restrict__ stA, const float* __restrict__ stB,
    const float* __restrict__ gamma, const float* __restrict__ beta,
    unsigned short* __restrict__ y) {
    constexpr int TPR = C / 8;
    int gid = blockIdx.x * 256 + threadIdx.x;
    int r = gid / TPR, t = gid % TPR;
    if (r > rows) return;
    short8 o8;
    if (r == rows) {
        for (int j = 0; j < 8; ++j) o8[j] = 0;
    } else {
        const float inv_n = 1.0f / (float)rows;
        const float* xr = x + (size_t)r * stride + t * 8;
        float4 v0 = *(const float4*)(xr);
        float4 v1 = *(const float4*)(xr + 4);
        float vv[8] = {v0.x, v0.y, v0.z, v0.w, v1.x, v1.y, v1.z, v1.w};
#pragma unroll
        for (int j = 0; j < 8; ++j) {
            int c = t * 8 + j;
            const float* st = (c < CSPLIT) ? stA : stB;
            int cc = (c < CSPLIT) ? c : c - CSPLIT;
            int cs = (c < CSPLIT) ? CSPLIT : (C - CSPLIT);
            float mu = st[cc] * inv_n;
            float var = st[cs + cc] * inv_n - mu * mu;
            float sc = gamma[c] * rsqrtf(var + EPS);
            float shf = beta[c] - mu * sc;
            float ov = fmaxf(0.f, fmaf(vv[j], sc, shf));
            o8[j] = (short)f2bf(ov);
        }
    }
    *(short8*)(y + (size_t)r * C + t * 8) = o8;
}

// One dispatch: all 5 weight transposes/casts f32 [K][CIN][COUT] -> bf16
// LANE-MAJOR fragment layout: within tap k, fragment (nt,kf) is 64 chunks of
// 16B, chunk index = lane (q*16+l15); chunk holds logical
// W^T[co=nt*16+l15][ci = kf*32 + q*8 + 0..7].
__device__ __forceinline__ void wt_seg(const float* W, unsigned short* WT,
                                       int id, int CIN, int COUT) {
    int r = id % (CIN * COUT);
    int t = id / (CIN * COUT);
    int co = r / CIN;
    int ci = r % CIN;
    int ksub = CIN >> 5;               // 1 for CIN=32, 2 for CIN=64
    int nt = co >> 4, l15 = co & 15;
    int kf = (ksub > 1) ? (ci >> 5) : 0;
    int qq = (ci >> 3) & 3;
    int e  = ci & 7;
    int off = ((nt * ksub + kf) * 64 + (qq * 16 + l15)) * 8 + e;
    WT[(size_t)t * CIN * COUT + off] = f2bf(W[(size_t)t * CIN * COUT + ci * COUT + co]);
}
__global__ __launch_bounds__(256) void wt_transpose_all(
    const float* w1, const float* wd, const float* w2, const float* w3,
    const float* wu, unsigned short* o1, unsigned short* od,
    unsigned short* o2, unsigned short* o3, unsigned short* ou) {
    int id = blockIdx.x * 256 + threadIdx.x;
    // segment sizes: 27648, 16384, 110592, 55296, 16384 (total 226304)
    if (id < 27648) { wt_seg(w1, o1, id, 32, 32); return; }
    id -= 27648;
    if (id < 16384) { wt_seg(wd, od, id, 32, 64); return; }
    id -= 16384;
    if (id < 110592) { wt_seg(w2, o2, id, 64, 64); return; }
    id -= 110592;
    if (id < 55296) { wt_seg(w3, o3, id, 64, 32); return; }
    id -= 55296;
    if (id < 16384) { wt_seg(wu, ou, id, 64, 32); return; }
}

// Deconv segment builder (per up_k segment, compacted (fine_row, coarse_row)).
__global__ __launch_bounds__(256) void build_rb_up(
    const int* __restrict__ up_cidx, const int* __restrict__ up_k,
    int rows, int cap, int2* __restrict__ rb, int* __restrict__ cnt) {
    const int s = blockIdx.y;
    const int lane = threadIdx.x & 63;
    const int wave = threadIdx.x >> 6;
    const long wbase = (long)blockIdx.x * 1024 + wave * 256;

    unsigned long long masks[4];
    int cs[4], ok[4], tot[4], wtotal = 0;
#pragma unroll
    for (int c = 0; c < 4; ++c) {
        long i = wbase + c * 64 + lane;
        int seg = (i < rows) ? up_k[i] : -1;
        cs[c] = (i < rows) ? up_cidx[i] : 0;
        ok[c] = (seg == s);
        masks[c] = __ballot(ok[c]);
        tot[c] = __popcll(masks[c]);
        wtotal += tot[c];
    }
    __shared__ int sh[5];
    if (lane == 0) sh[wave] = wtotal;
    __syncthreads();
    if (threadIdx.x == 0) {
        int t = sh[0] + sh[1] + sh[2] + sh[3];
        sh[4] = t ? atomicAdd(&cnt[s * 32], t) : 0;
    }
    __syncthreads();
    int base = sh[4];
    for (int w = 0; w < wave; ++w) base += sh[w];
#pragma unroll
    for (int c = 0; c < 4; ++c) {
        if (ok[c]) {
            int rank = __popcll(masks[c] & ((1ull << lane) - 1ull));
            int j = base + rank;
            if (j < cap)
                rb[(size_t)s * cap + j] = make_int2((int)(wbase + c * 64 + lane), cs[c]);
        }
        base += tot[c];
    }
}

// ---- conv kernels ----------------------------------------------------------

// Dense-over-taps gather conv: MT=4 half-tap A register double-buffer +
// phase-blocked LDS B (TPP taps/phase, double-buffered, 1 barrier/phase).
template <int CIN, int COT, int NTAP, int MT, int TPP>
__global__ __launch_bounds__(256) void conv_dense(
    const unsigned short* __restrict__ fpad,
    const int* __restrict__ nbr,
    const unsigned short* __restrict__ WT,
    float* __restrict__ out,
    float* __restrict__ stats,
    int rows, int P, int out_stride) {
    constexpr int N_SUB = COT / 16;
    constexpr int K_SUB = CIN / 32;
    constexpr int MH = MT / 2;
    constexpr int TAP_SH = COT * CIN;                 // shorts per tap
    constexpr int PHASES = (NTAP + TPP - 1) / TPP;
    constexpr int NBUF = (PHASES > 1) ? 2 : 1;
    __shared__ unsigned short ldsB[NBUF][TPP * TAP_SH];
    const int tid = threadIdx.x;
    const int wave = tid >> 6;
    const int lane = tid & 63;
    const int q = lane >> 4;
    const int l15 = lane & 15;
    const int m0 = blockIdx.x * (64 * MT) + wave * (16 * MT);

    int mrow[MT], mok[MT];
#pragma unroll
    for (int mt = 0; mt < MT; ++mt) {
        int m = m0 + mt * 16 + l15;
        mok[mt] = (m < rows);
        mrow[mt] = mok[mt] ? m : 0;
    }

    f32x4 acc[MT][N_SUB];
#pragma unroll
    for (int mt = 0; mt < MT; ++mt)
#pragma unroll
        for (int nt = 0; nt < N_SUB; ++nt) acc[mt][nt] = (f32x4){0.f, 0.f, 0.f, 0.f};

    short8 aLo[MH][K_SUB], aHi[MH][K_SUB];
    short8 b[N_SUB][K_SUB];
    int idxN[MT];

    auto stage_phase = [&](int ph, int buf) {
        const int t0 = ph * TPP;
        const int cnt = (t0 + TPP <= NTAP) ? TPP : (NTAP - t0);
        const unsigned short* src = WT + (size_t)t0 * TAP_SH;
        const int tot = cnt * TAP_SH / 512;           // 1KB stage instrs
        for (int j = wave; j < tot; j += 4) {
            __builtin_amdgcn_global_load_lds(
                (const __attribute__((address_space(1))) void*)(src + j * 512 + lane * 8),
                (__attribute__((address_space(3))) void*)(&ldsB[buf][j * 512]),
                16, 0, 0);
        }
    };
    auto load_b_lds = [&](int buf, int kk) {
#pragma unroll
        for (int nt = 0; nt < N_SUB; ++nt)
#pragma unroll
            for (int kf = 0; kf < K_SUB; ++kf)
                b[nt][kf] = *(const short8*)(
                    &ldsB[buf][kk * TAP_SH + ((nt * K_SUB + kf) * 64 + lane) * 8]);
    };
    auto load_idx = [&](int k) {
#pragma unroll
        for (int mt = 0; mt < MT; ++mt)
            idxN[mt] = mok[mt] ? nbr[(size_t)k * rows + mrow[mt]] : P;
    };
    auto gather_half = [&](short8 (&a)[MH][K_SUB], int hoff) {
#pragma unroll
        for (int h = 0; h < MH; ++h) {
            const unsigned short* ap = fpad + (size_t)idxN[hoff + h] * CIN + q * 8;
#pragma unroll
            for (int kf = 0; kf < K_SUB; ++kf)
                a[h][kf] = *(const short8*)(ap + kf * 32);
        }
    };
    auto gather_half0 = [&](short8 (&a)[MH][K_SUB], int hoff, int k0) {
        // prologue variant: gathers tap k0 via fresh idx reads (no idxN clobber)
#pragma unroll
        for (int h = 0; h < MH; ++h) {
            int idx = mok[hoff + h] ? nbr[(size_t)k0 * rows + mrow[hoff + h]] : P;
            const unsigned short* ap = fpad + (size_t)idx * CIN + q * 8;
#pragma unroll
            for (int kf = 0; kf < K_SUB; ++kf)
                a[h][kf] = *(const short8*)(ap + kf * 32);
        }
    };
    auto mfma_half = [&](short8 (&a)[MH][K_SUB], int hoff) {
#pragma unroll
        for (int h = 0; h < MH; ++h)
#pragma unroll
            for (int nt = 0; nt < N_SUB; ++nt)
#pragma unroll
                for (int kf = 0; kf < K_SUB; ++kf)
                    acc[hoff + h][nt] = __builtin_amdgcn_mfma_f32_16x16x32_bf16(
                        a[h][kf], b[nt][kf], acc[hoff + h][nt], 0, 0, 0);
    };

    // Prologue: stage phase-0 B; gather tap-0 A (both halves); idxN <- tap 1.
    stage_phase(0, 0);
    load_idx(0);
    gather_half0(aLo, 0, 0);
    gather_half0(aHi, MH, 0);
    if (NTAP > 1) load_idx(1);
    __syncthreads();   // vmcnt drain: ldsB[0] + tap-0 A ready

#pragma unroll
    for (int k = 0; k < NTAP; ++k) {
        constexpr int NB1 = NBUF - 1;
        const int ph = k / TPP;
        const int cur = ph & NB1;
        const bool more = (k + 1 < NTAP);
        load_b_lds(cur, k - ph * TPP);              // ds_read tap k's B
        if (k % TPP == 0 && ph + 1 < PHASES)
            stage_phase(ph + 1, (ph + 1) & NB1);    // async stage next phase
        // low half: consume tap k, refill with tap k+1 (idxN)
        mfma_half(aLo, 0);
        if (more) gather_half(aLo, 0);
        // high half: consume tap k, refill, prefetch next idx
        mfma_half(aHi, MH);
        if (more) {
            gather_half(aHi, MH);
            if (k + 2 < NTAP) load_idx(k + 2);
        }
        if ((k + 1) % TPP == 0 && (k + 1) < NTAP)
            __syncthreads();                        // one drain per phase
    }

    // Direct write, once per output row.
#pragma unroll
    for (int mt = 0; mt < MT; ++mt)
#pragma unroll
        for (int i = 0; i < 4; ++i) {
            int row = m0 + mt * 16 + q * 4 + i;
            if (row < rows) {
#pragma unroll
                for (int nt = 0; nt < N_SUB; ++nt)
                    out[(size_t)row * out_stride + nt * 16 + l15] = acc[mt][nt][i];
            }
        }

    // Fused BN stats (final values; OOB lanes hold acc==0).
    if (stats) {
        __shared__ float ssum[COT], ssq[COT];
        for (int i = tid; i < 2 * COT; i += 256)
            (i < COT ? ssum[i] : ssq[i - COT]) = 0.f;
        __syncthreads();
#pragma unroll
        for (int nt = 0; nt < N_SUB; ++nt) {
            float s = 0.f, s2 = 0.f;
#pragma unroll
            for (int mt = 0; mt < MT; ++mt)
#pragma unroll
                for (int i = 0; i < 4; ++i) {
                    float v = acc[mt][nt][i];
                    s += v; s2 += v * v;
                }
            s += __shfl_xor(s, 16);  s += __shfl_xor(s, 32);
            s2 += __shfl_xor(s2, 16); s2 += __shfl_xor(s2, 32);
            if (q == 0) {
                atomicAdd(&ssum[nt * 16 + l15], s);
                atomicAdd(&ssq[nt * 16 + l15], s2);
            }
        }
        __syncthreads();
        if (tid < COT) {
            atomicAdd(&stats[tid], ssum[tid]);
            atomicAdd(&stats[COT + tid], ssq[tid]);
        }
    }
}

// Segmented gather-GEMM over compacted rulebook tiles (deconv only), with
// coalesced lane-major B loads.
template <int CIN, int COT, bool ATOMIC>
__global__ __launch_bounds__(256) void conv_sparse(
    const unsigned short* __restrict__ fpad,
    const int2* __restrict__ rb,
    const int* __restrict__ cnt,
    const unsigned short* __restrict__ WT,
    float* __restrict__ out,
    float* __restrict__ stats,
    int cap, int kskip, int P, int out_stride) {
    constexpr int N_SUB = COT / 16;
    constexpr int K_SUB = CIN / 32;
    const int tap = blockIdx.y;
    int n = cnt[tap * 32];
    n = n < cap ? n : cap;
    const int nbx = gridDim.x;
    const int step = (nbx >> 3) | 1;
    const int px = (int)((blockIdx.x + (unsigned)tap * step) % (unsigned)nbx);
    const int base0 = px * 128;
    if (base0 >= n) return;
    const int k = tap + (tap >= kskip ? 1 : 0);
    const int tid = threadIdx.x;
    const int wave = tid >> 6;
    const int lane = tid & 63;
    const int q = lane >> 4;
    const int l15 = lane & 15;
    const int base = base0 + wave * 32;
    const int2* seg = rb + (size_t)tap * cap;

    f32x4 acc[2][N_SUB];
#pragma unroll
    for (int mt = 0; mt < 2; ++mt)
#pragma unroll
        for (int nt = 0; nt < N_SUB; ++nt) acc[mt][nt] = (f32x4){0.f, 0.f, 0.f, 0.f};

    short8 a[2][K_SUB], b[N_SUB][K_SUB];
#pragma unroll
    for (int mt = 0; mt < 2; ++mt) {
        int j = base + mt * 16 + l15;
        int src = (j < n) ? seg[j].y : P;
#pragma unroll
        for (int kf = 0; kf < K_SUB; ++kf)
            a[mt][kf] = *(const short8*)(fpad + (size_t)src * CIN + kf * 32 + q * 8);
    }
    const unsigned short* Wk = WT + (size_t)k * COT * CIN;
#pragma unroll
    for (int nt = 0; nt < N_SUB; ++nt)
#pragma unroll
        for (int kf = 0; kf < K_SUB; ++kf)
            b[nt][kf] = *(const short8*)(Wk + ((nt * K_SUB + kf) * 64 + lane) * 8);
#pragma unroll
    for (int mt = 0; mt < 2; ++mt)
#pragma unroll
        for (int nt = 0; nt < N_SUB; ++nt)
#pragma unroll
            for (int kf = 0; kf < K_SUB; ++kf)
                acc[mt][nt] = __builtin_amdgcn_mfma_f32_16x16x32_bf16(
                    a[mt][kf], b[nt][kf], acc[mt][nt], 0, 0, 0);

#pragma unroll
    for (int mt = 0; mt < 2; ++mt)
#pragma unroll
        for (int i = 0; i < 4; ++i) {
            int j = base + mt * 16 + q * 4 + i;
            if (j < n) {
                int row = seg[j].x;
                float* o = out + (size_t)row * out_stride + l15;
#pragma unroll
                for (int nt = 0; nt < N_SUB; ++nt) {
                    if (ATOMIC) atomicAdd(o + nt * 16, acc[mt][nt][i]);
                    else        o[nt * 16] = acc[mt][nt][i];
                }
            }
        }

    // Fused BN stats (final-value writes only): OOB lanes hold acc==0.
    if (!ATOMIC && stats) {
        __shared__ float ssum[COT], ssq[COT];
        for (int i = tid; i < 2 * COT; i += 256)
            (i < COT ? ssum[i] : ssq[i - COT]) = 0.f;
        __syncthreads();
#pragma unroll
        for (int nt = 0; nt < N_SUB; ++nt) {
            float s = 0.f, s2 = 0.f;
#pragma unroll
            for (int mt = 0; mt < 2; ++mt)
#pragma unroll
                for (int i = 0; i < 4; ++i) {
                    float v = acc[mt][nt][i];
                    s += v; s2 += v * v;
                }
            s += __shfl_xor(s, 16);  s += __shfl_xor(s, 32);
            s2 += __shfl_xor(s2, 16); s2 += __shfl_xor(s2, 32);
            if (q == 0) {
                atomicAdd(&ssum[nt * 16 + l15], s);
                atomicAdd(&ssq[nt * 16 + l15], s2);
            }
        }
        __syncthreads();
        if (tid < COT) {
            atomicAdd(&stats[tid], ssum[tid]);
            atomicAdd(&stats[COT + tid], ssq[tid]);
        }
    }
}

static inline int ceil_div(long a, long b) { return (int)((a + b - 1) / b); }

extern "C" void kernel_launch(void* const* d_in, const int* in_sizes, int n_in,
                              void* d_out, int out_size, void* d_ws, size_t ws_size,
                              hipStream_t stream) {
    const float* feat   = (const float*)d_in[0];
    const float* w_sub1 = (const float*)d_in[1];
    const float* w_down = (const float*)d_in[2];
    const float* w_sub2 = (const float*)d_in[3];
    const float* w_up   = (const float*)d_in[4];
    const float* w_sub3 = (const float*)d_in[5];
    const float* g1 = (const float*)d_in[6],  *b1 = (const float*)d_in[7];
    const float* g2 = (const float*)d_in[8],  *b2 = (const float*)d_in[9];
    const float* g3 = (const float*)d_in[10], *b3 = (const float*)d_in[11];
    const float* g4 = (const float*)d_in[12], *b4 = (const float*)d_in[13];
    const float* g5 = (const float*)d_in[14], *b5 = (const float*)d_in[15];
    const int* nbr_fine   = (const int*)d_in[16];
    const int* nbr_coarse = (const int*)d_in[17];
    const int* down_idx   = (const int*)d_in[18];
    const int* up_cidx    = (const int*)d_in[19];
    const int* up_k       = (const int*)d_in[20];

    const int N = in_sizes[0] / 32;
    const int M = in_sizes[17] / 27;
    const size_t maxr = (size_t)((N > M ? N : M) + 1);

    const int cap_u = 32768;     // up segments (~25.6k expected)

    char* ws = (char*)d_ws;
    size_t off = 0;
    auto alloc = [&](size_t bytes) { void* p = ws + off; off += (bytes + 255) & ~(size_t)255; return p; };
    float* stats = (float*)alloc(768 * sizeof(float));
    int*   cnts  = (int*)alloc(1024 * sizeof(int));              // up: 8 taps * 32 stride
    const size_t zero_words = off / 4;                            // stats..cnts contiguous
    float* D  = (float*)alloc((size_t)N * 64 * sizeof(float));    // concat buf [skip|up]
    float* Cf = (float*)alloc((size_t)M * 64 * sizeof(float));    // coarse f32 temp
    unsigned short* FA = (unsigned short*)alloc(maxr * 64 * 2);
    unsigned short* FB = (unsigned short*)alloc(maxr * 64 * 2);
    int2* rb_up = (int2*)alloc((size_t)8 * cap_u * sizeof(int2));
    unsigned short* w1t = (unsigned short*)alloc(27 * 32 * 32 * 2);
    unsigned short* wdt = (unsigned short*)alloc(8 * 32 * 64 * 2);
    unsigned short* w2t = (unsigned short*)alloc(27 * 64 * 64 * 2);
    unsigned short* w3t = (unsigned short*)alloc(27 * 64 * 32 * 2);
    unsigned short* wupT = (unsigned short*)alloc(8 * 64 * 32 * 2);

    float* st0 = stats + 0 * 128;   // feat (32 ch)
    float* st1 = stats + 1 * 128;   // conv1 out (32 ch, fused)
    float* st2 = stats + 2 * 128;   // down out (64 ch, fused)
    float* st3 = stats + 3 * 128;   // conv2 out (64 ch, fused)
    float* st4 = stats + 4 * 128;   // deconv out (32 ch, fused)
    int* cnt_up = cnts;

    // ---- setup ----
    zero_kernel<<<ceil_div((long)zero_words, 256), 256, 0, stream>>>(stats, (long)zero_words);
    wt_transpose_all<<<ceil_div(226304, 256), 256, 0, stream>>>(
        w_sub1, w_down, w_sub2, w_sub3, w_up, w1t, wdt, w2t, w3t, wupT);
    build_rb_up<<<dim3(ceil_div(N, 1024), 8), 256, 0, stream>>>(
        up_cidx, up_k, N, cap_u, rb_up, cnt_up);

    // 1) BN0+ReLU(feat) -> FA [(N+1)x32 bf16]
    bn_stats<32><<<256, 256, 0, stream>>>(feat, N, 32, st0);
    bn_norm_relu_bf16<32, 32><<<ceil_div((long)(N + 1) * 4, 256), 256, 0, stream>>>(
        feat, N, 32, st0, st0, g1, b1, FA);
    // 2) conv1 (27, 32->32): MT=4, TPP=4 (16KB LDS, 6 barriers) -> D[:,0:32], st1
    conv_dense<32, 32, 27, 4, 4><<<ceil_div(N, 256), 256, 0, stream>>>(
        FA, nbr_fine, w1t, D, st1, N, N, 64);
    // 3) BN1+ReLU(skip) -> FB
    bn_norm_relu_bf16<32, 32><<<ceil_div((long)(N + 1) * 4, 256), 256, 0, stream>>>(
        D, N, 64, st1, st1, g2, b2, FB);
    // 4) down conv (8, 32->64): MT=4, TPP=4 (32KB, 1 barrier) -> Cf, st2
    conv_dense<32, 64, 8, 4, 4><<<ceil_div(M, 256), 256, 0, stream>>>(
        FB, down_idx, wdt, Cf, st2, M, N, 64);
    // 5) BN2+ReLU(Cf) -> FA [(M+1)x64]
    bn_norm_relu_bf16<64, 64><<<ceil_div((long)(M + 1) * 8, 256), 256, 0, stream>>>(
        Cf, M, 64, st2, st2, g3, b3, FA);
    // 6) conv2 (27, 64->64): MT=4, TPP=2 (32KB, 13 barriers) -> Cf, st3
    conv_dense<64, 64, 27, 4, 2><<<ceil_div(M, 256), 256, 0, stream>>>(
        FA, nbr_coarse, w2t, Cf, st3, M, M, 64);
    // 7) BN3+ReLU(Cf) -> FB [(M+1)x64]
    bn_norm_relu_bf16<64, 64><<<ceil_div((long)(M + 1) * 8, 256), 256, 0, stream>>>(
        Cf, M, 64, st3, st3, g4, b4, FB);
    // 8) deconv (64->32): segments, direct writes -> D[:,32:64]; fused stats st4
    conv_sparse<64, 32, false><<<dim3(cap_u / 128, 8), 256, 0, stream>>>(
        FB, rb_up, cnt_up, wupT, D + 32, st4, cap_u, 99, M, 64);
    // 9) BN4+ReLU(D) -> FA [(N+1)x64]; low 32 ch stats = st1, high 32 = st4
    bn_norm_relu_bf16<64, 32><<<ceil_div((long)(N + 1) * 8, 256), 256, 0, stream>>>(
        D, N, 64, st1, st4, g5, b5, FA);
    // 10) conv3 (27, 64->32): MT=4, TPP=4 (32KB, 6 barriers) -> d_out
    conv_dense<64, 32, 27, 4, 4><<<ceil_div(N, 256), 256, 0, stream>>>(
        FA, nbr_fine, w3t, (float*)d_out, nullptr, N, N, 32);
}

// Round 16
// 516.923 us; speedup vs baseline: 1.1108x; 1.1108x over previous
//
#include <hip/hip_runtime.h>

// ---------------------------------------------------------------------------
// Sparse UNet forward — round 23: level-specialized hybrid.
//   Fine level (occupancy 1.19%, ~2.4k entries/tap): conv1/conv3 = dense
//   center GEMM (identity gather, streaming) + compacted rulebook sparse taps
//   (tap-staggered atomics, 63k entries total) — r10 structure + lane-major B.
//   Coarse level (9.15%): keep r21 conv_dense (MT=2, phase-blocked LDS-B,
//   best measured: conv2=87us). Deconv/BN unchanged from r21 (540us best).
// ---------------------------------------------------------------------------

#define EPS 1e-4f

typedef __attribute__((ext_vector_type(8))) short short8;   // 8 x bf16
typedef __attribute__((ext_vector_type(4))) float f32x4;

__device__ __forceinline__ unsigned short f2bf(float f) {
    union { float f; unsigned int u; } v; v.f = f;
    unsigned int r = v.u + 0x7fffu + ((v.u >> 16) & 1u);   // RNE
    return (unsigned short)(r >> 16);
}

__global__ void zero_kernel(float* p, long n) {
    long i = (long)blockIdx.x * 256 + threadIdx.x;
    if (i < n) p[i] = 0.f;
}

// Per-channel sum / sumsq -> stats[0:C], stats[C:2C] (atomic accumulate).
template <int C>
__global__ __launch_bounds__(256) void bn_stats(const float* __restrict__ x,
                                                int rows, int stride,
                                                float* __restrict__ stats) {
    const int tid = threadIdx.x;
    const int c = tid & (C - 1);
    const int g = tid / C;
    const int GR = 256 / C;
    float s = 0.f, s2 = 0.f;
    for (int r = blockIdx.x * GR + g; r < rows; r += gridDim.x * GR) {
        float v = x[(size_t)r * stride + c];
        s += v; s2 += v * v;
    }
    __shared__ float sh[2][256];
    sh[0][tid] = s; sh[1][tid] = s2;
    __syncthreads();
    for (int off = 128; off >= C; off >>= 1) {
        if (tid < off) { sh[0][tid] += sh[0][tid + off]; sh[1][tid] += sh[1][tid + off]; }
        __syncthreads();
    }
    if (tid < C) {
        atomicAdd(&stats[c], sh[0][tid]);
        atomicAdd(&stats[C + c], sh[1][tid]);
    }
}

// BN finalize + ReLU -> bf16. Output packed (rows+1) x C, sentinel row zeroed.
template <int C, int CSPLIT>
__global__ __launch_bounds__(256) void bn_norm_relu_bf16(
    const float* __restrict__ x, int rows, int stride,
    const float* __restrict__ stA, const float* __restrict__ stB,
    const float* __restrict__ gamma, const float* __restrict__ beta,
    unsigned short* __restrict__ y) {
    constexpr int TPR = C / 8;
    int gid = blockIdx.x * 256 + threadIdx.x;
    int r = gid / TPR, t = gid % TPR;
    if (r > rows) return;
    short8 o8;
    if (r == rows) {
        for (int j = 0; j < 8; ++j) o8[j] = 0;
    } else {
        const float inv_n = 1.0f / (float)rows;
        const float* xr = x + (size_t)r * stride + t * 8;
        float4 v0 = *(const float4*)(xr);
        float4 v1 = *(const float4*)(xr + 4);
        float vv[8] = {v0.x, v0.y, v0.z, v0.w, v1.x, v1.y, v1.z, v1.w};
#pragma unroll
        for (int j = 0; j < 8; ++j) {
            int c = t * 8 + j;
            const float* st = (c < CSPLIT) ? stA : stB;
            int cc = (c < CSPLIT) ? c : c - CSPLIT;
            int cs = (c < CSPLIT) ? CSPLIT : (C - CSPLIT);
            float mu = st[cc] * inv_n;
            float var = st[cs + cc] * inv_n - mu * mu;
            float sc = gamma[c] * rsqrtf(var + EPS);
            float shf = beta[c] - mu * sc;
            float ov = fmaxf(0.f, fmaf(vv[j], sc, shf));
            o8[j] = (short)f2bf(ov);
        }
    }
    *(short8*)(y + (size_t)r * C + t * 8) = o8;
}

// One dispatch: all 5 weight transposes/casts f32 [K][CIN][COUT] -> bf16
// LANE-MAJOR fragment layout: within tap k, fragment (nt,kf) is 64 chunks of
// 16B, chunk index = lane (q*16+l15).
__device__ __forceinline__ void wt_seg(const float* W, unsigned short* WT,
                                       int id, int CIN, int COUT) {
    int r = id % (CIN * COUT);
    int t = id / (CIN * COUT);
    int co = r / CIN;
    int ci = r % CIN;
    int ksub = CIN >> 5;               // 1 for CIN=32, 2 for CIN=64
    int nt = co >> 4, l15 = co & 15;
    int kf = (ksub > 1) ? (ci >> 5) : 0;
    int qq = (ci >> 3) & 3;
    int e  = ci & 7;
    int off = ((nt * ksub + kf) * 64 + (qq * 16 + l15)) * 8 + e;
    WT[(size_t)t * CIN * COUT + off] = f2bf(W[(size_t)t * CIN * COUT + ci * COUT + co]);
}
__global__ __launch_bounds__(256) void wt_transpose_all(
    const float* w1, const float* wd, const float* w2, const float* w3,
    const float* wu, unsigned short* o1, unsigned short* od,
    unsigned short* o2, unsigned short* o3, unsigned short* ou) {
    int id = blockIdx.x * 256 + threadIdx.x;
    // segment sizes: 27648, 16384, 110592, 55296, 16384 (total 226304)
    if (id < 27648) { wt_seg(w1, o1, id, 32, 32); return; }
    id -= 27648;
    if (id < 16384) { wt_seg(wd, od, id, 32, 64); return; }
    id -= 16384;
    if (id < 110592) { wt_seg(w2, o2, id, 64, 64); return; }
    id -= 110592;
    if (id < 55296) { wt_seg(w3, o3, id, 64, 32); return; }
    id -= 55296;
    if (id < 16384) { wt_seg(wu, ou, id, 64, 32); return; }
}

// Fine-level compacted per-tap rulebook (r9/r10, verified fast).
__global__ __launch_bounds__(256) void build_rb_tap(
    const int* __restrict__ nbr, int rows, int P, int cap, int kskip,
    int2* __restrict__ rb, int* __restrict__ cnt) {
    const int tap = blockIdx.y;
    const int k = tap + (tap >= kskip ? 1 : 0);
    const int* nk = nbr + (size_t)k * rows;
    const int lane = threadIdx.x & 63;
    const int wave = threadIdx.x >> 6;
    const long wbase = (long)blockIdx.x * 1024 + wave * 256;

    unsigned long long masks[4];
    int vs[4], tot[4], wtotal = 0;
#pragma unroll
    for (int c = 0; c < 4; ++c) {
        long m = wbase + c * 64 + lane;
        int v = (m < rows) ? nk[m] : P;
        vs[c] = v;
        masks[c] = __ballot(v != P);
        tot[c] = __popcll(masks[c]);
        wtotal += tot[c];
    }
    __shared__ int sh[5];
    if (lane == 0) sh[wave] = wtotal;
    __syncthreads();
    if (threadIdx.x == 0) {
        int t = sh[0] + sh[1] + sh[2] + sh[3];
        sh[4] = t ? atomicAdd(&cnt[tap * 32], t) : 0;
    }
    __syncthreads();
    int base = sh[4];
    for (int w = 0; w < wave; ++w) base += sh[w];
#pragma unroll
    for (int c = 0; c < 4; ++c) {
        if (vs[c] != P) {
            int rank = __popcll(masks[c] & ((1ull << lane) - 1ull));
            int j = base + rank;
            if (j < cap)
                rb[(size_t)tap * cap + j] = make_int2((int)(wbase + c * 64 + lane), vs[c]);
        }
        base += tot[c];
    }
}

// Deconv segment builder (per up_k segment, compacted (fine_row, coarse_row)).
__global__ __launch_bounds__(256) void build_rb_up(
    const int* __restrict__ up_cidx, const int* __restrict__ up_k,
    int rows, int cap, int2* __restrict__ rb, int* __restrict__ cnt) {
    const int s = blockIdx.y;
    const int lane = threadIdx.x & 63;
    const int wave = threadIdx.x >> 6;
    const long wbase = (long)blockIdx.x * 1024 + wave * 256;

    unsigned long long masks[4];
    int cs[4], ok[4], tot[4], wtotal = 0;
#pragma unroll
    for (int c = 0; c < 4; ++c) {
        long i = wbase + c * 64 + lane;
        int seg = (i < rows) ? up_k[i] : -1;
        cs[c] = (i < rows) ? up_cidx[i] : 0;
        ok[c] = (seg == s);
        masks[c] = __ballot(ok[c]);
        tot[c] = __popcll(masks[c]);
        wtotal += tot[c];
    }
    __shared__ int sh[5];
    if (lane == 0) sh[wave] = wtotal;
    __syncthreads();
    if (threadIdx.x == 0) {
        int t = sh[0] + sh[1] + sh[2] + sh[3];
        sh[4] = t ? atomicAdd(&cnt[s * 32], t) : 0;
    }
    __syncthreads();
    int base = sh[4];
    for (int w = 0; w < wave; ++w) base += sh[w];
#pragma unroll
    for (int c = 0; c < 4; ++c) {
        if (ok[c]) {
            int rank = __popcll(masks[c] & ((1ull << lane) - 1ull));
            int j = base + rank;
            if (j < cap)
                rb[(size_t)s * cap + j] = make_int2((int)(wbase + c * 64 + lane), cs[c]);
        }
        base += tot[c];
    }
}

// ---- conv kernels ----------------------------------------------------------

// Dense center-tap GEMM (identity gather, streaming): out[m] = fpad[m] @ Wk.
template <int CIN, int COT>
__global__ __launch_bounds__(256) void conv_center(
    const unsigned short* __restrict__ fpad,
    const unsigned short* __restrict__ Wk,
    float* __restrict__ out, int rows, int out_stride) {
    constexpr int N_SUB = COT / 16;
    constexpr int K_SUB = CIN / 32;
    const int tid = threadIdx.x;
    const int wave = tid >> 6;
    const int lane = tid & 63;
    const int q = lane >> 4;
    const int l15 = lane & 15;
    const int m0 = blockIdx.x * 128 + wave * 32;

    f32x4 acc[2][N_SUB];
#pragma unroll
    for (int mt = 0; mt < 2; ++mt)
#pragma unroll
        for (int nt = 0; nt < N_SUB; ++nt) acc[mt][nt] = (f32x4){0.f, 0.f, 0.f, 0.f};

    short8 a[2][K_SUB], b[N_SUB][K_SUB];
#pragma unroll
    for (int mt = 0; mt < 2; ++mt) {
        int m = m0 + mt * 16 + l15;
        int src = (m < rows) ? m : rows;   // rows = sentinel (zero row)
#pragma unroll
        for (int kf = 0; kf < K_SUB; ++kf)
            a[mt][kf] = *(const short8*)(fpad + (size_t)src * CIN + kf * 32 + q * 8);
    }
#pragma unroll
    for (int nt = 0; nt < N_SUB; ++nt)
#pragma unroll
        for (int kf = 0; kf < K_SUB; ++kf)
            b[nt][kf] = *(const short8*)(Wk + ((nt * K_SUB + kf) * 64 + lane) * 8);
#pragma unroll
    for (int mt = 0; mt < 2; ++mt)
#pragma unroll
        for (int nt = 0; nt < N_SUB; ++nt)
#pragma unroll
            for (int kf = 0; kf < K_SUB; ++kf)
                acc[mt][nt] = __builtin_amdgcn_mfma_f32_16x16x32_bf16(
                    a[mt][kf], b[nt][kf], acc[mt][nt], 0, 0, 0);
#pragma unroll
    for (int mt = 0; mt < 2; ++mt)
#pragma unroll
        for (int i = 0; i < 4; ++i) {
            int row = m0 + mt * 16 + q * 4 + i;
            if (row < rows) {
#pragma unroll
                for (int nt = 0; nt < N_SUB; ++nt)
                    out[(size_t)row * out_stride + nt * 16 + l15] = acc[mt][nt][i];
            }
        }
}

// Sparse-tap gather-GEMM over compacted rulebook tiles (fine taps: atomic;
// deconv: direct write + fused stats). Tap-staggered block mapping.
template <int CIN, int COT, bool ATOMIC>
__global__ __launch_bounds__(256) void conv_sparse(
    const unsigned short* __restrict__ fpad,
    const int2* __restrict__ rb,
    const int* __restrict__ cnt,
    const unsigned short* __restrict__ WT,
    float* __restrict__ out,
    float* __restrict__ stats,
    int cap, int kskip, int P, int out_stride) {
    constexpr int N_SUB = COT / 16;
    constexpr int K_SUB = CIN / 32;
    const int tap = blockIdx.y;
    int n = cnt[tap * 32];
    n = n < cap ? n : cap;
    const int nbx = gridDim.x;
    const int step = (nbx >> 3) | 1;
    const int px = (int)((blockIdx.x + (unsigned)tap * step) % (unsigned)nbx);
    const int base0 = px * 128;
    if (base0 >= n && !(!ATOMIC && stats)) return;
    const int k = tap + (tap >= kskip ? 1 : 0);
    const int tid = threadIdx.x;
    const int wave = tid >> 6;
    const int lane = tid & 63;
    const int q = lane >> 4;
    const int l15 = lane & 15;
    const int base = base0 + wave * 32;
    const int2* seg = rb + (size_t)tap * cap;

    f32x4 acc[2][N_SUB];
#pragma unroll
    for (int mt = 0; mt < 2; ++mt)
#pragma unroll
        for (int nt = 0; nt < N_SUB; ++nt) acc[mt][nt] = (f32x4){0.f, 0.f, 0.f, 0.f};

    if (base0 < n) {
        short8 a[2][K_SUB], b[N_SUB][K_SUB];
#pragma unroll
        for (int mt = 0; mt < 2; ++mt) {
            int j = base + mt * 16 + l15;
            int src = (j < n) ? seg[j].y : P;
#pragma unroll
            for (int kf = 0; kf < K_SUB; ++kf)
                a[mt][kf] = *(const short8*)(fpad + (size_t)src * CIN + kf * 32 + q * 8);
        }
        const unsigned short* Wk = WT + (size_t)k * COT * CIN;
#pragma unroll
        for (int nt = 0; nt < N_SUB; ++nt)
#pragma unroll
            for (int kf = 0; kf < K_SUB; ++kf)
                b[nt][kf] = *(const short8*)(Wk + ((nt * K_SUB + kf) * 64 + lane) * 8);
#pragma unroll
        for (int mt = 0; mt < 2; ++mt)
#pragma unroll
            for (int nt = 0; nt < N_SUB; ++nt)
#pragma unroll
                for (int kf = 0; kf < K_SUB; ++kf)
                    acc[mt][nt] = __builtin_amdgcn_mfma_f32_16x16x32_bf16(
                        a[mt][kf], b[nt][kf], acc[mt][nt], 0, 0, 0);

#pragma unroll
        for (int mt = 0; mt < 2; ++mt)
#pragma unroll
            for (int i = 0; i < 4; ++i) {
                int j = base + mt * 16 + q * 4 + i;
                if (j < n) {
                    int row = seg[j].x;
                    float* o = out + (size_t)row * out_stride + l15;
#pragma unroll
                    for (int nt = 0; nt < N_SUB; ++nt) {
                        if (ATOMIC) atomicAdd(o + nt * 16, acc[mt][nt][i]);
                        else        o[nt * 16] = acc[mt][nt][i];
                    }
                }
            }
    }

    // Fused BN stats (final-value writes only): OOB lanes hold acc==0.
    if (!ATOMIC && stats) {
        __shared__ float ssum[COT], ssq[COT];
        for (int i = tid; i < 2 * COT; i += 256)
            (i < COT ? ssum[i] : ssq[i - COT]) = 0.f;
        __syncthreads();
#pragma unroll
        for (int nt = 0; nt < N_SUB; ++nt) {
            float s = 0.f, s2 = 0.f;
#pragma unroll
            for (int mt = 0; mt < 2; ++mt)
#pragma unroll
                for (int i = 0; i < 4; ++i) {
                    float v = acc[mt][nt][i];
                    s += v; s2 += v * v;
                }
            s += __shfl_xor(s, 16);  s += __shfl_xor(s, 32);
            s2 += __shfl_xor(s2, 16); s2 += __shfl_xor(s2, 32);
            if (q == 0) {
                atomicAdd(&ssum[nt * 16 + l15], s);
                atomicAdd(&ssq[nt * 16 + l15], s2);
            }
        }
        __syncthreads();
        if (tid < COT) {
            atomicAdd(&stats[tid], ssum[tid]);
            atomicAdd(&stats[COT + tid], ssq[tid]);
        }
    }
}

// Dense-over-taps gather conv (coarse level): MT=2 half... full-tap A register
// double-buffer + phase-blocked LDS B (TPP taps/phase, 1 barrier/phase). r21.
template <int CIN, int COT, int NTAP, int MT, int TPP>
__global__ __launch_bounds__(256) void conv_dense(
    const unsigned short* __restrict__ fpad,
    const int* __restrict__ nbr,
    const unsigned short* __restrict__ WT,
    float* __restrict__ out,
    float* __restrict__ stats,
    int rows, int P, int out_stride) {
    constexpr int N_SUB = COT / 16;
    constexpr int K_SUB = CIN / 32;
    constexpr int TAP_SH = COT * CIN;                 // shorts per tap
    constexpr int PHASES = (NTAP + TPP - 1) / TPP;
    constexpr int NBUF = (PHASES > 1) ? 2 : 1;
    __shared__ unsigned short ldsB[NBUF][TPP * TAP_SH];
    const int tid = threadIdx.x;
    const int wave = tid >> 6;
    const int lane = tid & 63;
    const int q = lane >> 4;
    const int l15 = lane & 15;
    const int m0 = blockIdx.x * (64 * MT) + wave * (16 * MT);

    int mrow[MT], mok[MT];
#pragma unroll
    for (int mt = 0; mt < MT; ++mt) {
        int m = m0 + mt * 16 + l15;
        mok[mt] = (m < rows);
        mrow[mt] = mok[mt] ? m : 0;
    }

    f32x4 acc[MT][N_SUB];
#pragma unroll
    for (int mt = 0; mt < MT; ++mt)
#pragma unroll
        for (int nt = 0; nt < N_SUB; ++nt) acc[mt][nt] = (f32x4){0.f, 0.f, 0.f, 0.f};

    short8 aA[MT][K_SUB], aB[MT][K_SUB];
    short8 b[N_SUB][K_SUB];
    int idxC[MT];

    auto stage_phase = [&](int ph, int buf) {
        const int t0 = ph * TPP;
        const int cnt = (t0 + TPP <= NTAP) ? TPP : (NTAP - t0);
        const unsigned short* src = WT + (size_t)t0 * TAP_SH;
        const int tot = cnt * TAP_SH / 512;           // 1KB stage instrs
        for (int j = wave; j < tot; j += 4) {
            __builtin_amdgcn_global_load_lds(
                (const __attribute__((address_space(1))) void*)(src + j * 512 + lane * 8),
                (__attribute__((address_space(3))) void*)(&ldsB[buf][j * 512]),
                16, 0, 0);
        }
    };
    auto load_b_lds = [&](int buf, int kk) {
#pragma unroll
        for (int nt = 0; nt < N_SUB; ++nt)
#pragma unroll
            for (int kf = 0; kf < K_SUB; ++kf)
                b[nt][kf] = *(const short8*)(
                    &ldsB[buf][kk * TAP_SH + ((nt * K_SUB + kf) * 64 + lane) * 8]);
    };
    auto load_idx = [&](int k) {
#pragma unroll
        for (int mt = 0; mt < MT; ++mt)
            idxC[mt] = mok[mt] ? nbr[(size_t)k * rows + mrow[mt]] : P;
    };
    auto gather = [&](short8 (&a)[MT][K_SUB]) {
#pragma unroll
        for (int mt = 0; mt < MT; ++mt) {
            const unsigned short* ap = fpad + (size_t)idxC[mt] * CIN + q * 8;
#pragma unroll
            for (int kf = 0; kf < K_SUB; ++kf)
                a[mt][kf] = *(const short8*)(ap + kf * 32);
        }
    };
    auto do_mfma = [&](short8 (&a)[MT][K_SUB]) {
#pragma unroll
        for (int mt = 0; mt < MT; ++mt)
#pragma unroll
            for (int nt = 0; nt < N_SUB; ++nt)
#pragma unroll
                for (int kf = 0; kf < K_SUB; ++kf)
                    acc[mt][nt] = __builtin_amdgcn_mfma_f32_16x16x32_bf16(
                        a[mt][kf], b[nt][kf], acc[mt][nt], 0, 0, 0);
    };

    // Prologue: stage phase-0 B; gather tap0 A into aA; idxC <- tap1.
    stage_phase(0, 0);
    load_idx(0);
    gather(aA);
    if (NTAP > 1) load_idx(1);
    __syncthreads();   // vmcnt drain: ldsB[0] + aA ready

#pragma unroll
    for (int k = 0; k < NTAP; ++k) {
        constexpr int NB1 = NBUF - 1;
        const int ph = k / TPP;
        const int cur = ph & NB1;
        load_b_lds(cur, k - ph * TPP);              // ds_read current tap's B
        if (k % TPP == 0 && ph + 1 < PHASES)
            stage_phase(ph + 1, (ph + 1) & NB1);    // async stage next phase
        if (k + 1 < NTAP) {
            if (k & 1) gather(aA); else gather(aB); // gather next tap's A
            if (k + 2 < NTAP) load_idx(k + 2);
        }
        if (k & 1) do_mfma(aB); else do_mfma(aA);
        if ((k + 1) % TPP == 0 && (k + 1) < NTAP)
            __syncthreads();                        // one drain per phase
    }

    // Direct write, once per output row.
#pragma unroll
    for (int mt = 0; mt < MT; ++mt)
#pragma unroll
        for (int i = 0; i < 4; ++i) {
            int row = m0 + mt * 16 + q * 4 + i;
            if (row < rows) {
#pragma unroll
                for (int nt = 0; nt < N_SUB; ++nt)
                    out[(size_t)row * out_stride + nt * 16 + l15] = acc[mt][nt][i];
            }
        }

    // Fused BN stats (final values; OOB lanes hold acc==0).
    if (stats) {
        __shared__ float ssum[COT], ssq[COT];
        for (int i = tid; i < 2 * COT; i += 256)
            (i < COT ? ssum[i] : ssq[i - COT]) = 0.f;
        __syncthreads();
#pragma unroll
        for (int nt = 0; nt < N_SUB; ++nt) {
            float s = 0.f, s2 = 0.f;
#pragma unroll
            for (int mt = 0; mt < MT; ++mt)
#pragma unroll
                for (int i = 0; i < 4; ++i) {
                    float v = acc[mt][nt][i];
                    s += v; s2 += v * v;
                }
            s += __shfl_xor(s, 16);  s += __shfl_xor(s, 32);
            s2 += __shfl_xor(s2, 16); s2 += __shfl_xor(s2, 32);
            if (q == 0) {
                atomicAdd(&ssum[nt * 16 + l15], s);
                atomicAdd(&ssq[nt * 16 + l15], s2);
            }
        }
        __syncthreads();
        if (tid < COT) {
            atomicAdd(&stats[tid], ssum[tid]);
            atomicAdd(&stats[COT + tid], ssq[tid]);
        }
    }
}

static inline int ceil_div(long a, long b) { return (int)((a + b - 1) / b); }

extern "C" void kernel_launch(void* const* d_in, const int* in_sizes, int n_in,
                              void* d_out, int out_size, void* d_ws, size_t ws_size,
                              hipStream_t stream) {
    const float* feat   = (const float*)d_in[0];
    const float* w_sub1 = (const float*)d_in[1];
    const float* w_down = (const float*)d_in[2];
    const float* w_sub2 = (const float*)d_in[3];
    const float* w_up   = (const float*)d_in[4];
    const float* w_sub3 = (const float*)d_in[5];
    const float* g1 = (const float*)d_in[6],  *b1 = (const float*)d_in[7];
    const float* g2 = (const float*)d_in[8],  *b2 = (const float*)d_in[9];
    const float* g3 = (const float*)d_in[10], *b3 = (const float*)d_in[11];
    const float* g4 = (const float*)d_in[12], *b4 = (const float*)d_in[13];
    const float* g5 = (const float*)d_in[14], *b5 = (const float*)d_in[15];
    const int* nbr_fine   = (const int*)d_in[16];
    const int* nbr_coarse = (const int*)d_in[17];
    const int* down_idx   = (const int*)d_in[18];
    const int* up_cidx    = (const int*)d_in[19];
    const int* up_k       = (const int*)d_in[20];

    const int N = in_sizes[0] / 32;
    const int M = in_sizes[17] / 27;
    const size_t maxr = (size_t)((N > M ? N : M) + 1);

    const int cap_f = 8192;      // fine per-tap (~2.4k expected, uniform random)
    const int cap_u = 32768;     // up segments (~25.6k expected)

    char* ws = (char*)d_ws;
    size_t off = 0;
    auto alloc = [&](size_t bytes) { void* p = ws + off; off += (bytes + 255) & ~(size_t)255; return p; };
    float* stats = (float*)alloc(768 * sizeof(float));
    int*   cnts  = (int*)alloc(4096 * sizeof(int));              // fine 26*32 + up 8*32
    const size_t zero_words = off / 4;                            // stats..cnts contiguous
    float* D  = (float*)alloc((size_t)N * 64 * sizeof(float));    // concat buf [skip|up]
    float* Cf = (float*)alloc((size_t)M * 64 * sizeof(float));    // coarse f32 temp
    unsigned short* FA = (unsigned short*)alloc(maxr * 64 * 2);
    unsigned short* FB = (unsigned short*)alloc(maxr * 64 * 2);
    int2* rb_fine = (int2*)alloc((size_t)26 * cap_f * sizeof(int2));
    int2* rb_up   = (int2*)alloc((size_t)8 * cap_u * sizeof(int2));
    unsigned short* w1t = (unsigned short*)alloc(27 * 32 * 32 * 2);
    unsigned short* wdt = (unsigned short*)alloc(8 * 32 * 64 * 2);
    unsigned short* w2t = (unsigned short*)alloc(27 * 64 * 64 * 2);
    unsigned short* w3t = (unsigned short*)alloc(27 * 64 * 32 * 2);
    unsigned short* wupT = (unsigned short*)alloc(8 * 64 * 32 * 2);

    float* st0 = stats + 0 * 128;   // feat (32 ch)
    float* st1 = stats + 1 * 128;   // conv1 out (32 ch, separate pass)
    float* st2 = stats + 2 * 128;   // down out (64 ch, fused)
    float* st3 = stats + 3 * 128;   // conv2 out (64 ch, fused)
    float* st4 = stats + 4 * 128;   // deconv out (32 ch, fused)
    int* cnt_fine = cnts;            // 26 taps * 32 stride
    int* cnt_up   = cnts + 26 * 32;

    // ---- setup ----
    zero_kernel<<<ceil_div((long)zero_words, 256), 256, 0, stream>>>(stats, (long)zero_words);
    wt_transpose_all<<<ceil_div(226304, 256), 256, 0, stream>>>(
        w_sub1, w_down, w_sub2, w_sub3, w_up, w1t, wdt, w2t, w3t, wupT);
    build_rb_tap<<<dim3(ceil_div(N, 1024), 26), 256, 0, stream>>>(
        nbr_fine, N, N, cap_f, 13, rb_fine, cnt_fine);
    build_rb_up<<<dim3(ceil_div(N, 1024), 8), 256, 0, stream>>>(
        up_cidx, up_k, N, cap_u, rb_up, cnt_up);

    // 1) BN0+ReLU(feat) -> FA [(N+1)x32 bf16]
    bn_stats<32><<<256, 256, 0, stream>>>(feat, N, 32, st0);
    bn_norm_relu_bf16<32, 32><<<ceil_div((long)(N + 1) * 4, 256), 256, 0, stream>>>(
        feat, N, 32, st0, st0, g1, b1, FA);
    // 2) conv1 (fine, 27, 32->32): center GEMM + sparse atomic taps -> D[:,0:32]
    conv_center<32, 32><<<ceil_div(N, 128), 256, 0, stream>>>(
        FA, w1t + (size_t)13 * 32 * 32, D, N, 64);
    conv_sparse<32, 32, true><<<dim3(cap_f / 128, 26), 256, 0, stream>>>(
        FA, rb_fine, cnt_fine, w1t, D, nullptr, cap_f, 13, N, 64);
    // 3) BN1 stats + BN1+ReLU(skip) -> FB
    bn_stats<32><<<256, 256, 0, stream>>>(D, N, 64, st1);
    bn_norm_relu_bf16<32, 32><<<ceil_div((long)(N + 1) * 4, 256), 256, 0, stream>>>(
        D, N, 64, st1, st1, g2, b2, FB);
    // 4) down conv (coarse, 8, 32->64): conv_dense TPP=8 (32KB, 1 barrier) -> Cf, st2
    conv_dense<32, 64, 8, 2, 8><<<ceil_div(M, 128), 256, 0, stream>>>(
        FB, down_idx, wdt, Cf, st2, M, N, 64);
    // 5) BN2+ReLU(Cf) -> FA [(M+1)x64]
    bn_norm_relu_bf16<64, 64><<<ceil_div((long)(M + 1) * 8, 256), 256, 0, stream>>>(
        Cf, M, 64, st2, st2, g3, b3, FA);
    // 6) conv2 (coarse, 27, 64->64): conv_dense TPP=3 (48KB, 9 barriers) -> Cf, st3
    conv_dense<64, 64, 27, 2, 3><<<ceil_div(M, 128), 256, 0, stream>>>(
        FA, nbr_coarse, w2t, Cf, st3, M, M, 64);
    // 7) BN3+ReLU(Cf) -> FB [(M+1)x64]
    bn_norm_relu_bf16<64, 64><<<ceil_div((long)(M + 1) * 8, 256), 256, 0, stream>>>(
        Cf, M, 64, st3, st3, g4, b4, FB);
    // 8) deconv (64->32): segments, direct writes -> D[:,32:64]; fused stats st4
    conv_sparse<64, 32, false><<<dim3(cap_u / 128, 8), 256, 0, stream>>>(
        FB, rb_up, cnt_up, wupT, D + 32, st4, cap_u, 99, M, 64);
    // 9) BN4+ReLU(D) -> FA [(N+1)x64]; low 32 ch stats = st1, high 32 = st4
    bn_norm_relu_bf16<64, 32><<<ceil_div((long)(N + 1) * 8, 256), 256, 0, stream>>>(
        D, N, 64, st1, st4, g5, b5, FA);
    // 10) conv3 (fine, 27, 64->32): center GEMM + sparse atomic taps -> d_out
    conv_center<64, 32><<<ceil_div(N, 128), 256, 0, stream>>>(
        FA, w3t + (size_t)13 * 64 * 32, (float*)d_out, N, 32);
    conv_sparse<64, 32, true><<<dim3(cap_f / 128, 26), 256, 0, stream>>>(
        FA, rb_fine, cnt_fine, w3t, (float*)d_out, nullptr, cap_f, 13, N, 32);
}